// Round 5
// baseline (157.204 us; speedup 1.0000x reference)
//
#include <hip/hip_runtime.h>
#include <hip/hip_fp16.h>
#include <stdint.h>

// Problem constants (fixed by the reference)
#define Bn 2
#define Qn 2048
#define Kn 2048
#define Hn 16
#define Dn 64
#define Rn 32

#define LOG2E_8 0.18033688011112042f   // 0.125 * log2(e)
#define MASK_NEG -14426.950408889634f  // -10000 * log2(e)

typedef __attribute__((ext_vector_type(8))) short short8v;   // 8 bf16 (4 VGPR) MFMA operand
typedef __attribute__((ext_vector_type(4))) float f32x4;     // MFMA accumulator
typedef __attribute__((ext_vector_type(4))) uint32_t u32x4;

static __device__ __forceinline__ uint16_t bf16rn(float f) {
  uint32_t u = __builtin_bit_cast(uint32_t, f);
  u += 0x7FFFu + ((u >> 16) & 1u);          // round-to-nearest-even
  return (uint16_t)(u >> 16);
}
static __device__ __forceinline__ float bf16f(uint16_t h) {
  uint32_t u = ((uint32_t)h) << 16;
  return __builtin_bit_cast(float, u);
}
static __device__ __forceinline__ float exp2a(float x) {
  float r; asm("v_exp_f32 %0, %1" : "=v"(r) : "v"(x)); return r;
}
static __device__ __forceinline__ uint32_t cvtpk(float lo, float hi) {
  uint32_t r; asm("v_cvt_pk_bf16_f32 %0, %1, %2" : "=v"(r) : "v"(lo), "v"(hi)); return r;
}
static __device__ __forceinline__ void gl_lds16(const void* g, void* l) {
  __builtin_amdgcn_global_load_lds((const __attribute__((address_space(1))) void*)g,
                                   (__attribute__((address_space(3))) void*)l, 16, 0, 0);
}

// ---------------- pre-pass 1: pack (rel_id | mask<<5) into one byte (6-bit table idx) ----
__global__ void pack_kernel(const int* __restrict__ ids,
                            const int* __restrict__ msk,
                            uint32_t* __restrict__ outp, int n4) {
  int i = blockIdx.x * 256 + threadIdx.x;
  if (i >= n4) return;
  int4 a = reinterpret_cast<const int4*>(ids)[i];
  int4 m = reinterpret_cast<const int4*>(msk)[i];
  uint32_t v = (uint32_t)((a.x | (m.x << 5)) & 0x3f)
             | ((uint32_t)((a.y | (m.y << 5)) & 0x3f) << 8)
             | ((uint32_t)((a.z | (m.z << 5)) & 0x3f) << 16)
             | ((uint32_t)((a.w | (m.w << 5)) & 0x3f) << 24);
  outp[i] = v;
}

// ---------------- pre-pass 2: K (hi/lo bf16) + V (bf16) into MFMA fragment layout ----
// Per (b,h,chunk c of 32 keys): 12288 B = kfrag[8 slots][64 lanes] uint4 + vfrag[4][64]
__global__ __launch_bounds__(256) void kfrag_kernel(const float* __restrict__ Kg,
                                                    const float* __restrict__ Vg,
                                                    uint8_t* __restrict__ frag) {
  const int bid = blockIdx.x;
  const int c = bid & 63;
  const int h = (bid >> 6) & 15;
  const int b = bid >> 10;
  uint8_t* panel = frag + (size_t)(b * 16 + h) * 786432u + (size_t)c * 12288u;
  uint4* kf = reinterpret_cast<uint4*>(panel);
  uint4* vf = reinterpret_cast<uint4*>(panel + 8192);
  const int tid = threadIdx.x;
  // K part
  const int sdq = tid & 7, srow = (tid >> 3) & 15, stile = tid >> 7;
  const int sg = sdq & 3, sdm = sdq >> 2;
  const float* kp = Kg + ((((size_t)b * Kn) + c * 32 + stile * 16 + srow) * Hn + h) * Dn + (sdm * 32 + sg * 4);
  const float4 x0 = *reinterpret_cast<const float4*>(kp);
  const float4 x1 = *reinterpret_cast<const float4*>(kp + 16);
  const float xs0[4] = {x0.x, x0.y, x0.z, x0.w};
  const float xs1[4] = {x1.x, x1.y, x1.z, x1.w};
  uint16_t hh[8], ll[8];
#pragma unroll
  for (int i = 0; i < 4; ++i) {
    const uint16_t h0 = bf16rn(xs0[i]);
    const uint16_t h1 = bf16rn(xs1[i]);
    hh[i] = h0; hh[4 + i] = h1;
    ll[i] = bf16rn(xs0[i] - bf16f(h0));
    ll[4 + i] = bf16rn(xs1[i] - bf16f(h1));
  }
  uint4 uh, ul;
  uh.x = hh[0] | ((uint32_t)hh[1] << 16); uh.y = hh[2] | ((uint32_t)hh[3] << 16);
  uh.z = hh[4] | ((uint32_t)hh[5] << 16); uh.w = hh[6] | ((uint32_t)hh[7] << 16);
  ul.x = ll[0] | ((uint32_t)ll[1] << 16); ul.y = ll[2] | ((uint32_t)ll[3] << 16);
  ul.z = ll[4] | ((uint32_t)ll[5] << 16); ul.w = ll[6] | ((uint32_t)ll[7] << 16);
  kf[(stile * 2 + sdm) * 64 + (srow + 16 * sg)] = uh;
  kf[(4 + stile * 2 + sdm) * 64 + (srow + 16 * sg)] = ul;
  // V part
  const int vd = tid & 63, vkq = tid >> 6;
  const float* vp = Vg + ((((size_t)b * Kn) + c * 32 + vkq * 4) * Hn + h) * Dn + vd;
  float v0[4], v1[4];
#pragma unroll
  for (int i = 0; i < 4; ++i) {
    v0[i] = vp[i * (Hn * Dn)];
    v1[i] = vp[(16 + i) * (Hn * Dn)];
  }
  uint4 uv;
  uv.x = bf16rn(v0[0]) | ((uint32_t)bf16rn(v0[1]) << 16);
  uv.y = bf16rn(v0[2]) | ((uint32_t)bf16rn(v0[3]) << 16);
  uv.z = bf16rn(v1[0]) | ((uint32_t)bf16rn(v1[1]) << 16);
  uv.w = bf16rn(v1[2]) | ((uint32_t)bf16rn(v1[3]) << 16);
  vf[(vd >> 4) * 64 + (vd & 15) + 16 * vkq] = uv;
}

// ---------------- attn5: R3 math + split-K(2). 128-q blocks, 32-key chunks, online SM ----
__global__ __launch_bounds__(256, 4) void attn5_kernel(
    const float* __restrict__ Qg, const float* __restrict__ Eg,
    const float* __restrict__ biasg, const uint8_t* __restrict__ packed,
    const uint8_t* __restrict__ kfragp, float* __restrict__ acc0p,
    float* __restrict__ acc1p, float* __restrict__ m0p, float* __restrict__ l0p,
    float* __restrict__ m1p, float* __restrict__ l1p) {
  // LDS (static 40960 B -> 4 blocks/CU exactly):
  //   [0,16384)  tab __half[128 q][64]  ([q][id]=+MASK_NEG masked, [q][32+id]=plain)
  //   prologue: [16384,32768) q_lds f32[64][64] ; [32768,40960) et f32[64][32]
  //   main:     [16384,28672) cbuf0 ; [28672,40960) cbuf1
  __shared__ alignas(16) char smem[40960];
  __half* const tab  = reinterpret_cast<__half*>(smem);
  float* const q_lds = reinterpret_cast<float*>(smem + 16384);
  float* const et    = reinterpret_cast<float*>(smem + 32768);
  char* const cb0 = smem + 16384;
  char* const cb1 = smem + 28672;

  const int tid = threadIdx.x;
  const int lane = tid & 63;
  const int w = tid >> 6;
  const int qr = lane & 15;
  const int g = lane >> 4;

  // XCD swizzle (1024 blocks = 8 XCDs x 128); qt fastest so neighbors share K panel in L2
  const int wi = (blockIdx.x & 7) * 128 + (blockIdx.x >> 3);
  const int qt = wi & 15;
  const int ks = (wi >> 4) & 1;
  const int h = (wi >> 5) & 15;
  const int b = wi >> 9;
  const int q0 = qt * 128;

  short8v qhi[2][2], qlo[2][2];

  // ---- prologue (R3-verified structure, resized buffers): Q frags + f16 score table ----
#pragma unroll
  for (int half = 0; half < 2; ++half) {
    {
      const int row = tid >> 2, dq = (tid & 3) * 16;
      const float4* s4 = reinterpret_cast<const float4*>(
          Qg + (((size_t)b * Qn + q0 + half * 64 + row) * Hn + h) * Dn + dq);
      float4* dst = reinterpret_cast<float4*>(&q_lds[row * 64 + dq]);
#pragma unroll
      for (int i = 0; i < 4; ++i) dst[i] = s4[i];
    }
    if (half == 0) {
      const int r = tid >> 3, d0 = (tid & 7) * 8;
      const float* src = Eg + ((r * Hn + h) * Dn + d0);
#pragma unroll
      for (int i = 0; i < 8; ++i) et[(d0 + i) * 32 + r] = src[i];
    }
    __syncthreads();
    // Q fragments for subtiles residing in this half
#pragma unroll
    for (int t = 0; t < 2; ++t) {
      const int ql = w * 32 + t * 16 + qr;
      if ((ql >> 6) == half) {
        const int rl = ql & 63;
#pragma unroll
        for (int dm = 0; dm < 2; ++dm) {
#pragma unroll
          for (int j = 0; j < 8; ++j) {
            const int dl = (j < 4) ? (4 * g + j) : (16 + 4 * g + (j - 4));
            const float x = q_lds[rl * 64 + dm * 32 + dl];
            const uint16_t hi = bf16rn(x);
            qhi[t][dm][j] = (short)hi;
            qlo[t][dm][j] = (short)bf16rn(x - bf16f(hi));
          }
        }
      }
    }
    // table rows of this half (log2 domain; masked/unmasked variants)
    {
      const int r = tid & 31, q8 = tid >> 5;
      float a8[8] = {0.f, 0.f, 0.f, 0.f, 0.f, 0.f, 0.f, 0.f};
      const float bias = biasg[r * Hn + h];
      for (int d = 0; d < 64; ++d) {
        const float e = et[d * 32 + r];
#pragma unroll
        for (int i = 0; i < 8; ++i) a8[i] += e * q_lds[(q8 * 8 + i) * 64 + d];
      }
#pragma unroll
      for (int i = 0; i < 8; ++i) {
        const float ar = LOG2E_8 * (a8[i] + bias);
        const int qq = half * 64 + q8 * 8 + i;
        tab[qq * 64 + r]      = __float2half(ar + MASK_NEG);  // masked
        tab[qq * 64 + 32 + r] = __float2half(ar);             // unmasked
      }
    }
    __syncthreads();
  }

  // ---- main loop setup (split ks covers keys [ks*1024, ks*1024+1024)) ----
  const uint8_t* sbase = kfragp + (size_t)(b * 16 + h) * 786432u +
                         (size_t)(ks * 32) * 12288u + (size_t)w * 3072 + (size_t)lane * 16;
  int64_t prow[2];
  int trow[2];
#pragma unroll
  for (int t = 0; t < 2; ++t) {
    prow[t] = ((int64_t)(b * Qn + q0 + w * 32 + t * 16 + qr)) * Kn + ks * 1024 + 4 * g;
    trow[t] = (w * 32 + t * 16 + qr) * 64;
  }

  uint32_t pc[2][2], pn[2][2] = {{0u, 0u}, {0u, 0u}};
#pragma unroll
  for (int t = 0; t < 2; ++t)
#pragma unroll
    for (int st = 0; st < 2; ++st)
      pc[t][st] = *reinterpret_cast<const uint32_t*>(packed + prow[t] + st * 16);

  char* cbc = cb0;
  char* cbn = cb1;
  {  // stage chunk 0 (after prologue: cb0 aliases q_lds, so not earlier)
    char* ld = cbc + w * 3072;
    gl_lds16(sbase, ld);
    gl_lds16(sbase + 1024, ld + 1024);
    gl_lds16(sbase + 2048, ld + 2048);
  }
  asm volatile("s_waitcnt vmcnt(0)" ::: "memory");
  __syncthreads();

  f32x4 acc[2][4] = {{{0.f,0.f,0.f,0.f},{0.f,0.f,0.f,0.f},{0.f,0.f,0.f,0.f},{0.f,0.f,0.f,0.f}},
                     {{0.f,0.f,0.f,0.f},{0.f,0.f,0.f,0.f},{0.f,0.f,0.f,0.f},{0.f,0.f,0.f,0.f}}};
  float mrun[2] = {-1e30f, -1e30f};
  float lrun[2] = {0.f, 0.f};  // per-lane partial; reduced in epilogue

  for (int c = 0; c < 32; ++c) {
    // prefetch next 32-key chunk: frags -> LDS (async), packed bytes -> regs
    if (c + 1 < 32) {
      const uint8_t* gs = sbase + (size_t)(c + 1) * 12288u;
      char* ld = cbn + w * 3072;
      gl_lds16(gs, ld); gl_lds16(gs + 1024, ld + 1024); gl_lds16(gs + 2048, ld + 2048);
      const int64_t kb = (int64_t)(c + 1) * 32;
#pragma unroll
      for (int t = 0; t < 2; ++t)
#pragma unroll
        for (int st = 0; st < 2; ++st)
          pn[t][st] = *reinterpret_cast<const uint32_t*>(packed + prow[t] + kb + st * 16);
    }

    // ---- QK^T (swapped): S^T = mfma(K, Q); hi*hi + lo*hi + hi*lo ----
    const short8v* kfs = reinterpret_cast<const short8v*>(cbc);
    f32x4 s[2][2] = {{{0.f,0.f,0.f,0.f},{0.f,0.f,0.f,0.f}},
                     {{0.f,0.f,0.f,0.f},{0.f,0.f,0.f,0.f}}};
    __builtin_amdgcn_s_setprio(1);
#pragma unroll
    for (int dm = 0; dm < 2; ++dm) {
      const short8v k0h = kfs[dm * 64 + lane];
      const short8v k1h = kfs[(2 + dm) * 64 + lane];
      const short8v k0l = kfs[(4 + dm) * 64 + lane];
      const short8v k1l = kfs[(6 + dm) * 64 + lane];
#pragma unroll
      for (int t = 0; t < 2; ++t) {
        s[t][0] = __builtin_amdgcn_mfma_f32_16x16x32_bf16(k0h, qhi[t][dm], s[t][0], 0, 0, 0);
        s[t][0] = __builtin_amdgcn_mfma_f32_16x16x32_bf16(k0l, qhi[t][dm], s[t][0], 0, 0, 0);
        s[t][0] = __builtin_amdgcn_mfma_f32_16x16x32_bf16(k0h, qlo[t][dm], s[t][0], 0, 0, 0);
        s[t][1] = __builtin_amdgcn_mfma_f32_16x16x32_bf16(k1h, qhi[t][dm], s[t][1], 0, 0, 0);
        s[t][1] = __builtin_amdgcn_mfma_f32_16x16x32_bf16(k1l, qhi[t][dm], s[t][1], 0, 0, 0);
        s[t][1] = __builtin_amdgcn_mfma_f32_16x16x32_bf16(k1h, qlo[t][dm], s[t][1], 0, 0, 0);
      }
    }
    __builtin_amdgcn_s_setprio(0);

    // V fragments (shared by both q-tiles)
    const short8v* vfs = reinterpret_cast<const short8v*>(cbc + 8192);
    short8v vv[4];
#pragma unroll
    for (int dt = 0; dt < 4; ++dt) vv[dt] = vfs[dt * 64 + lane];

    // ---- per-tile: table gather + online softmax + PV (R3-verified math) ----
#pragma unroll
    for (int t = 0; t < 2; ++t) {
      float sv[8];
#pragma unroll
      for (int st = 0; st < 2; ++st) {
        const uint32_t pw = pc[t][st];
#pragma unroll
        for (int r = 0; r < 4; ++r) {
          const uint32_t v = (pw >> (8 * r)) & 63u;
          sv[st * 4 + r] = fmaf(LOG2E_8, s[t][st][r], __half2float(tab[trow[t] + (int)v]));
        }
      }
      float mx = fmaxf(fmaxf(fmaxf(sv[0], sv[1]), fmaxf(sv[2], sv[3])),
                       fmaxf(fmaxf(sv[4], sv[5]), fmaxf(sv[6], sv[7])));
      mx = fmaxf(mx, __shfl_xor(mx, 16));
      mx = fmaxf(mx, __shfl_xor(mx, 32));
      if (__any(mx > mrun[t] + 8.f)) {  // defer-max (T13)
        const float mnew = fmaxf(mrun[t], mx);
        const float sc = exp2a(mrun[t] - mnew);
        mrun[t] = mnew;
        f32x4 scv;
        scv[0] = __shfl(sc, 4 * g + 0); scv[1] = __shfl(sc, 4 * g + 1);
        scv[2] = __shfl(sc, 4 * g + 2); scv[3] = __shfl(sc, 4 * g + 3);
        acc[t][0] *= scv; acc[t][1] *= scv; acc[t][2] *= scv; acc[t][3] *= scv;
        lrun[t] *= sc;
      }
      float pv[8];
      float ps = 0.f;
#pragma unroll
      for (int i = 0; i < 8; ++i) { pv[i] = exp2a(sv[i] - mrun[t]); ps += pv[i]; }
      lrun[t] += ps;
      u32x4 pu;
      pu[0] = cvtpk(pv[0], pv[1]); pu[1] = cvtpk(pv[2], pv[3]);
      pu[2] = cvtpk(pv[4], pv[5]); pu[3] = cvtpk(pv[6], pv[7]);
      const short8v pa = __builtin_bit_cast(short8v, pu);
      __builtin_amdgcn_s_setprio(1);
#pragma unroll
      for (int dt = 0; dt < 4; ++dt)
        acc[t][dt] = __builtin_amdgcn_mfma_f32_16x16x32_bf16(pa, vv[dt], acc[t][dt], 0, 0, 0);
      __builtin_amdgcn_s_setprio(0);
    }

#pragma unroll
    for (int t = 0; t < 2; ++t) { pc[t][0] = pn[t][0]; pc[t][1] = pn[t][1]; }

    asm volatile("s_waitcnt vmcnt(0)" ::: "memory");
    __syncthreads();
    char* tmp = cbc; cbc = cbn; cbn = tmp;
  }

  // ---- epilogue: write RAW partial acc + per-row (m, l); merge kernel combines ----
  float* const accdst = ks ? acc1p : acc0p;
  float* const mdst = ks ? m1p : m0p;
  float* const ldst = ks ? l1p : l0p;
#pragma unroll
  for (int t = 0; t < 2; ++t) {
    float lt = lrun[t];
    lt += __shfl_xor(lt, 16);
    lt += __shfl_xor(lt, 32);
    if (lane < 16) {
      const size_t j = ((size_t)b * Qn + q0 + w * 32 + t * 16 + lane) * Hn + h;
      mdst[j] = mrun[t];   // uniform across lanes (tile-wide max)
      ldst[j] = lt;
    }
#pragma unroll
    for (int dt = 0; dt < 4; ++dt)
#pragma unroll
      for (int r = 0; r < 4; ++r) {
        const int qrow = q0 + w * 32 + t * 16 + 4 * g + r;
        accdst[(((size_t)b * Qn + qrow) * Hn + h) * Dn + dt * 16 + qr] = acc[t][dt][r];
      }
  }
}

// ---------------- merge: standard two-way flash combine ----------------
__global__ __launch_bounds__(256) void merge5_kernel(float* __restrict__ out,
                                                     const float* __restrict__ pp,
                                                     const float* __restrict__ m0p,
                                                     const float* __restrict__ l0p,
                                                     const float* __restrict__ m1p,
                                                     const float* __restrict__ l1p) {
  const int i = blockIdx.x * 256 + threadIdx.x;  // float4 index (grid exact)
  const float4 a = reinterpret_cast<const float4*>(out)[i];
  const float4 c = reinterpret_cast<const float4*>(pp)[i];
  const int j = i >> 4;  // 16 float4 per (b,q,h)
  const float m0 = m0p[j], m1 = m1p[j];
  const float M = fmaxf(m0, m1);
  const float a0 = exp2a(m0 - M);
  const float a1 = exp2a(m1 - M);
  const float inv = 1.0f / (l0p[j] * a0 + l1p[j] * a1);
  float4 r;
  r.x = (a.x * a0 + c.x * a1) * inv;
  r.y = (a.y * a0 + c.y * a1) * inv;
  r.z = (a.z * a0 + c.z * a1) * inv;
  r.w = (a.w * a0 + c.w * a1) * inv;
  reinterpret_cast<float4*>(out)[i] = r;
}

// ---------------- fallback: R3-verified kernel (ws >= 33.6 MB) ----------------
__global__ __launch_bounds__(256, 2) void attn3_kernel(
    const float* __restrict__ Qg, const float* __restrict__ Eg,
    const float* __restrict__ biasg, const uint8_t* __restrict__ packed,
    const uint8_t* __restrict__ frag, float* __restrict__ outg) {
  __shared__ alignas(16) char smem[66048];
  __half* const tab   = reinterpret_cast<__half*>(smem);
  float* const q_lds  = reinterpret_cast<float*>(smem + 16896);
  float* const et_lds = reinterpret_cast<float*>(smem + 34304);
  char* const cb0 = smem + 16896;
  char* const cb1 = smem + 41472;

  const int tid = threadIdx.x;
  const int lane = tid & 63;
  const int w = tid >> 6;
  const int qr = lane & 15;
  const int g = lane >> 4;

  const int wi = (blockIdx.x & 7) * 64 + (blockIdx.x >> 3);
  const int qt = wi & 15;
  const int h = (wi >> 4) & 15;
  const int b = wi >> 8;
  const int q0 = qt * 128;

  short8v qhi[2][2], qlo[2][2];

#pragma unroll
  for (int half = 0; half < 2; ++half) {
    {
      const int row = tid >> 2, dq = (tid & 3) * 16;
      const float4* s4 = reinterpret_cast<const float4*>(
          Qg + (((size_t)b * Qn + q0 + half * 64 + row) * Hn + h) * Dn + dq);
      float4* dst = reinterpret_cast<float4*>(&q_lds[row * 68 + dq]);
#pragma unroll
      for (int i = 0; i < 4; ++i) dst[i] = s4[i];
    }
    if (half == 0) {
      const int r = tid >> 3, d0 = (tid & 7) * 8;
      const float* src = Eg + ((r * Hn + h) * Dn + d0);
#pragma unroll
      for (int i = 0; i < 8; ++i) et_lds[(d0 + i) * 33 + r] = src[i];
    }
    __syncthreads();
#pragma unroll
    for (int t = 0; t < 2; ++t) {
      const int ql = w * 32 + t * 16 + qr;
      if ((ql >> 6) == half) {
        const int rl = ql & 63;
#pragma unroll
        for (int dm = 0; dm < 2; ++dm) {
#pragma unroll
          for (int j = 0; j < 8; ++j) {
            const int dl = (j < 4) ? (4 * g + j) : (16 + 4 * g + (j - 4));
            const float x = q_lds[rl * 68 + dm * 32 + dl];
            const uint16_t hi = bf16rn(x);
            qhi[t][dm][j] = (short)hi;
            qlo[t][dm][j] = (short)bf16rn(x - bf16f(hi));
          }
        }
      }
    }
    {
      const int r = tid & 31, q8 = tid >> 5;
      float a8[8] = {0.f, 0.f, 0.f, 0.f, 0.f, 0.f, 0.f, 0.f};
      const float bias = biasg[r * Hn + h];
      for (int d = 0; d < 64; ++d) {
        const float e = et_lds[d * 33 + r];
#pragma unroll
        for (int i = 0; i < 8; ++i) a8[i] += e * q_lds[(q8 * 8 + i) * 68 + d];
      }
#pragma unroll
      for (int i = 0; i < 8; ++i) {
        const float ar = LOG2E_8 * (a8[i] + bias);
        const int qq = half * 64 + q8 * 8 + i;
        tab[qq * 66 + r]      = __float2half(ar + MASK_NEG);
        tab[qq * 66 + 32 + r] = __float2half(ar);
      }
    }
    __syncthreads();
  }

  const uint8_t* panel = frag + (size_t)(b * 16 + h) * 786432u;
  const uint8_t* sbase = panel + (size_t)w * 3072 + (size_t)lane * 16;

  const int64_t prow0 = ((int64_t)(b * Qn + q0 + w * 32 + qr)) * Kn + 4 * g;
  const int64_t prow1 = prow0 + (int64_t)16 * Kn;
  const int trow0 = (w * 32 + qr);
  const int trow1 = trow0 + 16;

  uint32_t pc[2][4], pn[2][4];
#pragma unroll
  for (int j = 0; j < 4; ++j) {
    pc[0][j] = *(const uint32_t*)(packed + prow0 + j * 16);
    pc[1][j] = *(const uint32_t*)(packed + prow1 + j * 16);
  }

  char* cbc = cb0;
  char* cbn = cb1;
#pragma unroll
  for (int sub = 0; sub < 2; ++sub) {
    const uint8_t* gs = sbase + sub * 12288;
    char* ld = cbc + sub * 12288 + w * 3072;
    gl_lds16(gs, ld); gl_lds16(gs + 1024, ld + 1024); gl_lds16(gs + 2048, ld + 2048);
  }
  asm volatile("s_waitcnt vmcnt(0)" ::: "memory");
  __syncthreads();

  f32x4 acc[2][4] = {{{0.f,0.f,0.f,0.f},{0.f,0.f,0.f,0.f},{0.f,0.f,0.f,0.f},{0.f,0.f,0.f,0.f}},
                     {{0.f,0.f,0.f,0.f},{0.f,0.f,0.f,0.f},{0.f,0.f,0.f,0.f},{0.f,0.f,0.f,0.f}}};
  float mrun[2] = {-1e30f, -1e30f};
  float lrun[2] = {0.f, 0.f};

  for (int c = 0; c < 32; ++c) {
    if (c + 1 < 32) {
#pragma unroll
      for (int sub = 0; sub < 2; ++sub) {
        const uint8_t* gs = sbase + (size_t)(2 * (c + 1) + sub) * 12288u;
        char* ld = cbn + sub * 12288 + w * 3072;
        gl_lds16(gs, ld); gl_lds16(gs + 1024, ld + 1024); gl_lds16(gs + 2048, ld + 2048);
      }
      const int64_t kb = (int64_t)(c + 1) * 64;
#pragma unroll
      for (int j = 0; j < 4; ++j) {
        pn[0][j] = *(const uint32_t*)(packed + prow0 + kb + j * 16);
        pn[1][j] = *(const uint32_t*)(packed + prow1 + kb + j * 16);
      }
    }

    const short8v* kbase = reinterpret_cast<const short8v*>(cbc);
    f32x4 s[2][4] = {{{0.f,0.f,0.f,0.f},{0.f,0.f,0.f,0.f},{0.f,0.f,0.f,0.f},{0.f,0.f,0.f,0.f}},
                     {{0.f,0.f,0.f,0.f},{0.f,0.f,0.f,0.f},{0.f,0.f,0.f,0.f},{0.f,0.f,0.f,0.f}}};
    __builtin_amdgcn_s_setprio(1);
#pragma unroll
    for (int sub = 0; sub < 2; ++sub) {
      const int sb = sub * 768;
#pragma unroll
      for (int dm = 0; dm < 2; ++dm) {
        const short8v k0h = kbase[sb + dm * 64 + lane];
        const short8v k1h = kbase[sb + (2 + dm) * 64 + lane];
        const short8v k0l = kbase[sb + (4 + dm) * 64 + lane];
        const short8v k1l = kbase[sb + (6 + dm) * 64 + lane];
        const int j0 = sub * 2, j1 = sub * 2 + 1;
        s[0][j0] = __builtin_amdgcn_mfma_f32_16x16x32_bf16(k0h, qhi[0][dm], s[0][j0], 0, 0, 0);
        s[0][j0] = __builtin_amdgcn_mfma_f32_16x16x32_bf16(k0l, qhi[0][dm], s[0][j0], 0, 0, 0);
        s[0][j0] = __builtin_amdgcn_mfma_f32_16x16x32_bf16(k0h, qlo[0][dm], s[0][j0], 0, 0, 0);
        s[0][j1] = __builtin_amdgcn_mfma_f32_16x16x32_bf16(k1h, qhi[0][dm], s[0][j1], 0, 0, 0);
        s[0][j1] = __builtin_amdgcn_mfma_f32_16x16x32_bf16(k1l, qhi[0][dm], s[0][j1], 0, 0, 0);
        s[0][j1] = __builtin_amdgcn_mfma_f32_16x16x32_bf16(k1h, qlo[0][dm], s[0][j1], 0, 0, 0);
        s[1][j0] = __builtin_amdgcn_mfma_f32_16x16x32_bf16(k0h, qhi[1][dm], s[1][j0], 0, 0, 0);
        s[1][j0] = __builtin_amdgcn_mfma_f32_16x16x32_bf16(k0l, qhi[1][dm], s[1][j0], 0, 0, 0);
        s[1][j0] = __builtin_amdgcn_mfma_f32_16x16x32_bf16(k0h, qlo[1][dm], s[1][j0], 0, 0, 0);
        s[1][j1] = __builtin_amdgcn_mfma_f32_16x16x32_bf16(k1h, qhi[1][dm], s[1][j1], 0, 0, 0);
        s[1][j1] = __builtin_amdgcn_mfma_f32_16x16x32_bf16(k1l, qhi[1][dm], s[1][j1], 0, 0, 0);
        s[1][j1] = __builtin_amdgcn_mfma_f32_16x16x32_bf16(k1h, qlo[1][dm], s[1][j1], 0, 0, 0);
      }
    }
    __builtin_amdgcn_s_setprio(0);

    short8v vvx[2][4];
#pragma unroll
    for (int sub = 0; sub < 2; ++sub) {
      const short8v* vb = reinterpret_cast<const short8v*>(cbc + sub * 12288 + 8192);
#pragma unroll
      for (int dt = 0; dt < 4; ++dt) vvx[sub][dt] = vb[dt * 64 + lane];
    }

#pragma unroll
    for (int t = 0; t < 2; ++t) {
      const int trow = t ? trow1 : trow0;
      float sv[16];
#pragma unroll
      for (int i = 0; i < 16; ++i) {
        const int j = i >> 2, r = i & 3;
        const uint32_t v = ((t ? pc[1][j] : pc[0][j]) >> (8 * r)) & 63u;
        sv[i] = fmaf(LOG2E_8, t ? s[1][j][r] : s[0][j][r], __half2float(tab[trow * 66 + (int)v]));
      }
      float mx = fmaxf(fmaxf(fmaxf(sv[0], sv[1]), fmaxf(sv[2], sv[3])),
                       fmaxf(fmaxf(sv[4], sv[5]), fmaxf(sv[6], sv[7])));
      mx = fmaxf(mx, fmaxf(fmaxf(fmaxf(sv[8], sv[9]), fmaxf(sv[10], sv[11])),
                           fmaxf(fmaxf(sv[12], sv[13]), fmaxf(sv[14], sv[15]))));
      mx = fmaxf(mx, __shfl_xor(mx, 16));
      mx = fmaxf(mx, __shfl_xor(mx, 32));
      if (__any(mx > mrun[t] + 8.f)) {
        const float mnew = fmaxf(mrun[t], mx);
        const float sc = exp2a(mrun[t] - mnew);
        mrun[t] = mnew;
        f32x4 scv;
        scv[0] = __shfl(sc, 4 * g + 0); scv[1] = __shfl(sc, 4 * g + 1);
        scv[2] = __shfl(sc, 4 * g + 2); scv[3] = __shfl(sc, 4 * g + 3);
        acc[t][0] *= scv; acc[t][1] *= scv; acc[t][2] *= scv; acc[t][3] *= scv;
        lrun[t] *= sc;
      }
      float pv[16];
      float ps = 0.f;
#pragma unroll
      for (int i = 0; i < 16; ++i) { pv[i] = exp2a(sv[i] - mrun[t]); ps += pv[i]; }
      lrun[t] += ps;
      u32x4 pu0, pu1;
      pu0[0] = cvtpk(pv[0], pv[1]);  pu0[1] = cvtpk(pv[2], pv[3]);
      pu0[2] = cvtpk(pv[4], pv[5]);  pu0[3] = cvtpk(pv[6], pv[7]);
      pu1[0] = cvtpk(pv[8], pv[9]);  pu1[1] = cvtpk(pv[10], pv[11]);
      pu1[2] = cvtpk(pv[12], pv[13]); pu1[3] = cvtpk(pv[14], pv[15]);
      const short8v pa0 = __builtin_bit_cast(short8v, pu0);
      const short8v pa1 = __builtin_bit_cast(short8v, pu1);
      __builtin_amdgcn_s_setprio(1);
#pragma unroll
      for (int dt = 0; dt < 4; ++dt) {
        acc[t][dt] = __builtin_amdgcn_mfma_f32_16x16x32_bf16(pa0, vvx[0][dt], acc[t][dt], 0, 0, 0);
        acc[t][dt] = __builtin_amdgcn_mfma_f32_16x16x32_bf16(pa1, vvx[1][dt], acc[t][dt], 0, 0, 0);
      }
      __builtin_amdgcn_s_setprio(0);
    }

#pragma unroll
    for (int j = 0; j < 4; ++j) { pc[0][j] = pn[0][j]; pc[1][j] = pn[1][j]; }

    asm volatile("s_waitcnt vmcnt(0)" ::: "memory");
    __syncthreads();
    char* tmp = cbc; cbc = cbn; cbn = tmp;
  }

#pragma unroll
  for (int t = 0; t < 2; ++t) {
    float lt = lrun[t];
    lt += __shfl_xor(lt, 16);
    lt += __shfl_xor(lt, 32);
    const float linv = 1.0f / lt;
    f32x4 lv;
    lv[0] = __shfl(linv, 4 * g + 0); lv[1] = __shfl(linv, 4 * g + 1);
    lv[2] = __shfl(linv, 4 * g + 2); lv[3] = __shfl(linv, 4 * g + 3);
#pragma unroll
    for (int dt = 0; dt < 4; ++dt) {
#pragma unroll
      for (int r = 0; r < 4; ++r) {
        const int qrow = q0 + w * 32 + t * 16 + 4 * g + r;
        outg[(((size_t)b * Qn + qrow) * Hn + h) * Dn + dt * 16 + qr] = acc[t][dt][r] * lv[r];
      }
    }
  }
}

extern "C" void kernel_launch(void* const* d_in, const int* in_sizes, int n_in,
                              void* d_out, int out_size, void* d_ws, size_t ws_size,
                              hipStream_t stream) {
  const float* Qg    = (const float*)d_in[0];
  const float* Kg    = (const float*)d_in[1];
  const float* Vg    = (const float*)d_in[2];
  const int*   maskg = (const int*)d_in[3];
  const int*   idsg  = (const int*)d_in[4];
  const float* Eg    = (const float*)d_in[5];
  const float* biasg = (const float*)d_in[6];
  float* outg = (float*)d_out;

  // ws layout
  const size_t oPack = 0;                // 8,388,608
  const size_t oK    = 8388608;          // +25,165,824 -> 33,554,432
  const size_t oPP   = 33554432;         // +16,777,216 -> 50,331,648
  const size_t oM0   = 50331648;         // +262,144
  const size_t oL0   = 50593792;         // +262,144
  const size_t oM1   = 50855936;         // +262,144
  const size_t oL1   = 51118080;         // +262,144 -> 51,380,224
  const size_t need5 = 51380224;
  const size_t need3 = 33554432;
  const int n4 = (Bn * Qn * Kn) / 4;

  uint8_t* ws = (uint8_t*)d_ws;

  if (ws_size >= need5) {
    pack_kernel<<<n4 / 256, 256, 0, stream>>>(idsg, maskg, (uint32_t*)(ws + oPack), n4);
    kfrag_kernel<<<Bn * Hn * 64, 256, 0, stream>>>(Kg, Vg, ws + oK);
    attn5_kernel<<<Bn * Hn * 2 * (Qn / 128), 256, 0, stream>>>(
        Qg, Eg, biasg, ws + oPack, ws + oK,
        outg, (float*)(ws + oPP), (float*)(ws + oM0), (float*)(ws + oL0),
        (float*)(ws + oM1), (float*)(ws + oL1));
    merge5_kernel<<<(Bn * Qn * Hn * Dn / 4) / 256, 256, 0, stream>>>(
        outg, (const float*)(ws + oPP), (const float*)(ws + oM0), (const float*)(ws + oL0),
        (const float*)(ws + oM1), (const float*)(ws + oL1));
  } else if (ws_size >= need3) {
    pack_kernel<<<n4 / 256, 256, 0, stream>>>(idsg, maskg, (uint32_t*)(ws + oPack), n4);
    kfrag_kernel<<<Bn * Hn * 64, 256, 0, stream>>>(Kg, Vg, ws + oK);
    attn3_kernel<<<Bn * Hn * (Qn / 128), 256, 0, stream>>>(
        Qg, Eg, biasg, ws + oPack, ws + oK, outg);
  }
}

// Round 8
// 107.600 us; speedup vs baseline: 1.4610x; 1.4610x over previous
//
#include <hip/hip_runtime.h>
#include <hip/hip_fp16.h>
#include <stdint.h>

// Problem constants (fixed by the reference)
#define Bn 2
#define Qn 2048
#define Kn 2048
#define Hn 16
#define Dn 64
#define Rn 32

#define LOG2E_8 0.18033688011112042f   // 0.125 * log2(e)
#define MASK_NEG -14426.950408889634f  // -10000 * log2(e)

typedef __attribute__((ext_vector_type(8))) short short8v;   // 8 bf16 (4 VGPR) MFMA operand
typedef __attribute__((ext_vector_type(4))) float f32x4;     // MFMA accumulator
typedef __attribute__((ext_vector_type(4))) uint32_t u32x4;

static __device__ __forceinline__ uint16_t bf16rn(float f) {
  uint32_t u = __builtin_bit_cast(uint32_t, f);
  u += 0x7FFFu + ((u >> 16) & 1u);          // round-to-nearest-even
  return (uint16_t)(u >> 16);
}
static __device__ __forceinline__ float bf16f(uint16_t h) {
  uint32_t u = ((uint32_t)h) << 16;
  return __builtin_bit_cast(float, u);
}
static __device__ __forceinline__ float exp2a(float x) {
  float r; asm("v_exp_f32 %0, %1" : "=v"(r) : "v"(x)); return r;
}
static __device__ __forceinline__ uint32_t cvtpk(float lo, float hi) {
  uint32_t r; asm("v_cvt_pk_bf16_f32 %0, %1, %2" : "=v"(r) : "v"(lo), "v"(hi)); return r;
}
static __device__ __forceinline__ void gl_lds16(const void* g, void* l) {
  __builtin_amdgcn_global_load_lds((const __attribute__((address_space(1))) void*)g,
                                   (__attribute__((address_space(3))) void*)l, 16, 0, 0);
}

// ---------------- pre-pass 1: pack (rel_id | mask<<5) into one byte (6-bit table idx) ----
__global__ void pack_kernel(const int* __restrict__ ids,
                            const int* __restrict__ msk,
                            uint32_t* __restrict__ outp, int n4) {
  int i = blockIdx.x * 256 + threadIdx.x;
  if (i >= n4) return;
  int4 a = reinterpret_cast<const int4*>(ids)[i];
  int4 m = reinterpret_cast<const int4*>(msk)[i];
  uint32_t v = (uint32_t)((a.x | (m.x << 5)) & 0x3f)
             | ((uint32_t)((a.y | (m.y << 5)) & 0x3f) << 8)
             | ((uint32_t)((a.z | (m.z << 5)) & 0x3f) << 16)
             | ((uint32_t)((a.w | (m.w << 5)) & 0x3f) << 24);
  outp[i] = v;
}

// ---------------- pre-pass 2: K (single bf16, pre-scaled by LOG2E_8) + V (bf16) ----------
// Per (b,h,chunk c of 32 keys): 8192 B = kfrag[4 slots][64 lanes] uint4
//                                       + vfrag[4 slots][64 lanes] uint4 (at +4096)
__global__ __launch_bounds__(256) void kfrag6_kernel(const float* __restrict__ Kg,
                                                     const float* __restrict__ Vg,
                                                     uint8_t* __restrict__ frag) {
  const int bid = blockIdx.x;
  const int c = bid & 63;
  const int h = (bid >> 6) & 15;
  const int b = bid >> 10;
  uint8_t* panel = frag + (size_t)(b * 16 + h) * 524288u + (size_t)c * 8192u;
  uint4* kf = reinterpret_cast<uint4*>(panel);
  uint4* vf = reinterpret_cast<uint4*>(panel + 4096);
  const int tid = threadIdx.x;
  // K part: hi bf16 only, scaled (folds 1/8 * log2e into the MFMA output)
  const int sdq = tid & 7, srow = (tid >> 3) & 15, stile = tid >> 7;
  const int sg = sdq & 3, sdm = sdq >> 2;
  const float* kp = Kg + ((((size_t)b * Kn) + c * 32 + stile * 16 + srow) * Hn + h) * Dn + (sdm * 32 + sg * 4);
  const float4 x0 = *reinterpret_cast<const float4*>(kp);
  const float4 x1 = *reinterpret_cast<const float4*>(kp + 16);
  const float xs0[4] = {x0.x * LOG2E_8, x0.y * LOG2E_8, x0.z * LOG2E_8, x0.w * LOG2E_8};
  const float xs1[4] = {x1.x * LOG2E_8, x1.y * LOG2E_8, x1.z * LOG2E_8, x1.w * LOG2E_8};
  uint4 uh;
  uh.x = bf16rn(xs0[0]) | ((uint32_t)bf16rn(xs0[1]) << 16);
  uh.y = bf16rn(xs0[2]) | ((uint32_t)bf16rn(xs0[3]) << 16);
  uh.z = bf16rn(xs1[0]) | ((uint32_t)bf16rn(xs1[1]) << 16);
  uh.w = bf16rn(xs1[2]) | ((uint32_t)bf16rn(xs1[3]) << 16);
  kf[(stile * 2 + sdm) * 64 + (srow + 16 * sg)] = uh;
  // V part (unscaled)
  const int vd = tid & 63, vkq = tid >> 6;
  const float* vp = Vg + ((((size_t)b * Kn) + c * 32 + vkq * 4) * Hn + h) * Dn + vd;
  float v0[4], v1[4];
#pragma unroll
  for (int i = 0; i < 4; ++i) {
    v0[i] = vp[i * (Hn * Dn)];
    v1[i] = vp[(16 + i) * (Hn * Dn)];
  }
  uint4 uv;
  uv.x = bf16rn(v0[0]) | ((uint32_t)bf16rn(v0[1]) << 16);
  uv.y = bf16rn(v0[2]) | ((uint32_t)bf16rn(v0[3]) << 16);
  uv.z = bf16rn(v1[0]) | ((uint32_t)bf16rn(v1[1]) << 16);
  uv.w = bf16rn(v1[2]) | ((uint32_t)bf16rn(v1[3]) << 16);
  vf[(vd >> 4) * 64 + (vd & 15) + 16 * vkq] = uv;
}

// ---------------- attn7: R6 math; fully disjoint LDS; sched_barrier-pinned waits ---------
__global__ __launch_bounds__(256, 2) void attn7_kernel(
    const float* __restrict__ Qg, const float* __restrict__ Eg,
    const float* __restrict__ biasg, const uint8_t* __restrict__ packed,
    const uint8_t* __restrict__ kfragp, float* __restrict__ outg) {
  // LDS (all regions DISJOINT — no aliasing anywhere):
  //   [0,16896)      tab __half[128][66]
  //   [16896,33280)  cbuf0 (16384 B = one 64-key chunk)
  //   [33280,49664)  cbuf1
  //   [49664,67072)  q_lds f32[64][68]   (prologue only)
  //   [67072,75520)  et_lds f32[64][33]  (prologue only)
  __shared__ alignas(16) char smem[75520];
  __half* const tab   = reinterpret_cast<__half*>(smem);
  char* const cb0 = smem + 16896;
  char* const cb1 = smem + 33280;
  float* const q_lds  = reinterpret_cast<float*>(smem + 49664);
  float* const et_lds = reinterpret_cast<float*>(smem + 67072);

  const int tid = threadIdx.x;
  const int lane = tid & 63;
  const int w = tid >> 6;
  const int qr = lane & 15;
  const int g = lane >> 4;

  // XCD-aware swizzle (512 blocks = 8 XCDs x 64)
  const int wi = (blockIdx.x & 7) * 64 + (blockIdx.x >> 3);
  const int qt = wi & 15;
  const int h = (wi >> 4) & 15;
  const int b = wi >> 8;
  const int q0 = qt * 128;

  // ---- issue chunk-0 stage at entry (cb0 is disjoint from all prologue buffers) ----
  const uint8_t* sbase = kfragp + (size_t)(b * 16 + h) * 524288u +
                         (size_t)w * 4096 + (size_t)lane * 16;
  {
    char* ld = cb0 + w * 4096;
    gl_lds16(sbase, ld);
    gl_lds16(sbase + 1024, ld + 1024);
    gl_lds16(sbase + 2048, ld + 2048);
    gl_lds16(sbase + 3072, ld + 3072);
  }

  short8v qhi[2][2];

  // ---- prologue (R3-verified structure): Q frags (hi only) + f16 score table ----
#pragma unroll
  for (int half = 0; half < 2; ++half) {
    {
      const int row = tid >> 2, dq = (tid & 3) * 16;
      const float4* s4 = reinterpret_cast<const float4*>(
          Qg + (((size_t)b * Qn + q0 + half * 64 + row) * Hn + h) * Dn + dq);
      float4* dst = reinterpret_cast<float4*>(&q_lds[row * 68 + dq]);
#pragma unroll
      for (int i = 0; i < 4; ++i) dst[i] = s4[i];
    }
    if (half == 0) {
      const int r = tid >> 3, d0 = (tid & 7) * 8;
      const float* src = Eg + ((r * Hn + h) * Dn + d0);
#pragma unroll
      for (int i = 0; i < 8; ++i) et_lds[(d0 + i) * 33 + r] = src[i];
    }
    __syncthreads();
#pragma unroll
    for (int t = 0; t < 2; ++t) {
      const int ql = w * 32 + t * 16 + qr;
      if ((ql >> 6) == half) {
        const int rl = ql & 63;
#pragma unroll
        for (int dm = 0; dm < 2; ++dm) {
#pragma unroll
          for (int j = 0; j < 8; ++j) {
            const int dl = (j < 4) ? (4 * g + j) : (16 + 4 * g + (j - 4));
            qhi[t][dm][j] = (short)bf16rn(q_lds[rl * 68 + dm * 32 + dl]);
          }
        }
      }
    }
    {
      const int r = tid & 31, q8 = tid >> 5;
      float a8[8] = {0.f, 0.f, 0.f, 0.f, 0.f, 0.f, 0.f, 0.f};
      const float bias = biasg[r * Hn + h];
      for (int d = 0; d < 64; ++d) {
        const float e = et_lds[d * 33 + r];
#pragma unroll
        for (int i = 0; i < 8; ++i) a8[i] += e * q_lds[(q8 * 8 + i) * 68 + d];
      }
#pragma unroll
      for (int i = 0; i < 8; ++i) {
        const float ar = LOG2E_8 * (a8[i] + bias);
        const int qq = half * 64 + q8 * 8 + i;
        tab[qq * 66 + r]      = __float2half(ar + MASK_NEG);  // masked
        tab[qq * 66 + 32 + r] = __float2half(ar);             // unmasked
      }
    }
    __syncthreads();
  }

  // ---- main loop setup ----
  int64_t prow[2];
  int trow[2];
#pragma unroll
  for (int t = 0; t < 2; ++t) {
    prow[t] = ((int64_t)(b * Qn + q0 + w * 32 + t * 16 + qr)) * Kn + 4 * g;
    trow[t] = (w * 32 + t * 16 + qr) * 66;
  }

  uint32_t pc[2][4], pn[2][4] = {{0u,0u,0u,0u},{0u,0u,0u,0u}};
#pragma unroll
  for (int t = 0; t < 2; ++t)
#pragma unroll
    for (int j = 0; j < 4; ++j)
      pc[t][j] = *reinterpret_cast<const uint32_t*>(packed + prow[t] + j * 16);

  char* cbc = cb0;
  char* cbn = cb1;
  // drain chunk-0 staging (prologue barriers already did, this is belt-and-braces)
  asm volatile("s_waitcnt vmcnt(0)" ::: "memory");
  __builtin_amdgcn_sched_barrier(0);
  __syncthreads();

  const short8v ones = {(short)0x3F80, (short)0x3F80, (short)0x3F80, (short)0x3F80,
                        (short)0x3F80, (short)0x3F80, (short)0x3F80, (short)0x3F80};

  f32x4 acc[2][4] = {{{0.f,0.f,0.f,0.f},{0.f,0.f,0.f,0.f},{0.f,0.f,0.f,0.f},{0.f,0.f,0.f,0.f}},
                     {{0.f,0.f,0.f,0.f},{0.f,0.f,0.f,0.f},{0.f,0.f,0.f,0.f},{0.f,0.f,0.f,0.f}}};
  f32x4 accl[2] = {{0.f,0.f,0.f,0.f},{0.f,0.f,0.f,0.f}};

  for (int c = 0; c < 32; ++c) {
    // prefetch next 64-key chunk: frags -> LDS (async), packed bytes -> regs
    if (c + 1 < 32) {
      const uint8_t* gs = sbase + (size_t)(c + 1) * 16384u;
      char* ld = cbn + w * 4096;
      gl_lds16(gs, ld); gl_lds16(gs + 1024, ld + 1024);
      gl_lds16(gs + 2048, ld + 2048); gl_lds16(gs + 3072, ld + 3072);
      const int64_t kb = (int64_t)(c + 1) * 64;
#pragma unroll
      for (int t = 0; t < 2; ++t)
#pragma unroll
        for (int j = 0; j < 4; ++j)
          pn[t][j] = *reinterpret_cast<const uint32_t*>(packed + prow[t] + kb + j * 16);
    }

    // ---- QK^T (swapped, single bf16): S^T = mfma(K~, Q), K~ pre-scaled to log2 dom ----
    const short8v* kfs = reinterpret_cast<const short8v*>(cbc);
    f32x4 s[2][4] = {{{0.f,0.f,0.f,0.f},{0.f,0.f,0.f,0.f},{0.f,0.f,0.f,0.f},{0.f,0.f,0.f,0.f}},
                     {{0.f,0.f,0.f,0.f},{0.f,0.f,0.f,0.f},{0.f,0.f,0.f,0.f},{0.f,0.f,0.f,0.f}}};
    __builtin_amdgcn_s_setprio(1);
#pragma unroll
    for (int sub = 0; sub < 2; ++sub) {
      const int sb = sub * 512;  // 8192 B / 16
#pragma unroll
      for (int dm = 0; dm < 2; ++dm) {
        const short8v k0 = kfs[sb + dm * 64 + lane];
        const short8v k1 = kfs[sb + (2 + dm) * 64 + lane];
#pragma unroll
        for (int t = 0; t < 2; ++t) {
          s[t][sub * 2 + 0] =
              __builtin_amdgcn_mfma_f32_16x16x32_bf16(k0, qhi[t][dm], s[t][sub * 2 + 0], 0, 0, 0);
          s[t][sub * 2 + 1] =
              __builtin_amdgcn_mfma_f32_16x16x32_bf16(k1, qhi[t][dm], s[t][sub * 2 + 1], 0, 0, 0);
        }
      }
    }
    __builtin_amdgcn_s_setprio(0);

    // V fragments (shared by both q-tiles)
    short8v vv[2][4];
#pragma unroll
    for (int sub = 0; sub < 2; ++sub) {
      const short8v* vb = reinterpret_cast<const short8v*>(cbc + sub * 8192 + 4096);
#pragma unroll
      for (int dt = 0; dt < 4; ++dt) vv[sub][dt] = vb[dt * 64 + lane];
    }

    // ---- per-tile: table gather + raw exp2 (no max tracking) + PV + ones-MFMA l ----
#pragma unroll
    for (int t = 0; t < 2; ++t) {
      float pv[16];
#pragma unroll
      for (int i = 0; i < 16; ++i) {
        const int j = i >> 2, r = i & 3;
        const uint32_t v = (pc[t][j] >> (8 * r)) & 63u;
        pv[i] = exp2a(s[t][j][r] + __half2float(tab[trow[t] + (int)v]));
      }
      u32x4 pu0, pu1;
      pu0[0] = cvtpk(pv[0], pv[1]);   pu0[1] = cvtpk(pv[2], pv[3]);
      pu0[2] = cvtpk(pv[4], pv[5]);   pu0[3] = cvtpk(pv[6], pv[7]);
      pu1[0] = cvtpk(pv[8], pv[9]);   pu1[1] = cvtpk(pv[10], pv[11]);
      pu1[2] = cvtpk(pv[12], pv[13]); pu1[3] = cvtpk(pv[14], pv[15]);
      const short8v pa0 = __builtin_bit_cast(short8v, pu0);
      const short8v pa1 = __builtin_bit_cast(short8v, pu1);
      __builtin_amdgcn_s_setprio(1);
#pragma unroll
      for (int dt = 0; dt < 4; ++dt) {
        acc[t][dt] = __builtin_amdgcn_mfma_f32_16x16x32_bf16(pa0, vv[0][dt], acc[t][dt], 0, 0, 0);
        acc[t][dt] = __builtin_amdgcn_mfma_f32_16x16x32_bf16(pa1, vv[1][dt], acc[t][dt], 0, 0, 0);
      }
      accl[t] = __builtin_amdgcn_mfma_f32_16x16x32_bf16(pa0, ones, accl[t], 0, 0, 0);
      accl[t] = __builtin_amdgcn_mfma_f32_16x16x32_bf16(pa1, ones, accl[t], 0, 0, 0);
      __builtin_amdgcn_s_setprio(0);
    }

#pragma unroll
    for (int t = 0; t < 2; ++t)
#pragma unroll
      for (int j = 0; j < 4; ++j) pc[t][j] = pn[t][j];

    asm volatile("s_waitcnt vmcnt(0)" ::: "memory");
    __builtin_amdgcn_sched_barrier(0);
    __syncthreads();
    char* tmp = cbc; cbc = cbn; cbn = tmp;
  }

  // ---- epilogue: accl rows align with acc rows -> zero shuffles ----
#pragma unroll
  for (int t = 0; t < 2; ++t) {
    f32x4 linv;
#pragma unroll
    for (int r = 0; r < 4; ++r) linv[r] = 1.0f / fmaxf(accl[t][r], 1e-35f);
#pragma unroll
    for (int dt = 0; dt < 4; ++dt)
#pragma unroll
      for (int r = 0; r < 4; ++r) {
        const int qrow = q0 + w * 32 + t * 16 + 4 * g + r;
        outg[(((size_t)b * Qn + qrow) * Hn + h) * Dn + dt * 16 + qr] = acc[t][dt][r] * linv[r];
      }
  }
}

// ---------------- fallback (ws too small): fully self-contained, no scratch ----------------
__global__ __launch_bounds__(256) void attn_old_kernel(
    const float* __restrict__ Qg, const float* __restrict__ Kg,
    const float* __restrict__ Vg, const int* __restrict__ maskg,
    const int* __restrict__ idsg, const float* __restrict__ Eg,
    const float* __restrict__ biasg, float* __restrict__ outg) {
  __shared__ alignas(16) char smem[34304];
  float* const allrel = reinterpret_cast<float*>(smem);
  float* const q_lds  = reinterpret_cast<float*>(smem + 8448);
  float* const et_lds = reinterpret_cast<float*>(smem + 25856);
  uint4* const kfrag  = reinterpret_cast<uint4*>(smem + 8448);
  uint4* const vfrag  = reinterpret_cast<uint4*>(smem + 16640);

  const int tid  = threadIdx.x;
  const int lane = tid & 63;
  const int w    = tid >> 6;
  const int qr   = lane & 15;
  const int g    = lane >> 4;

  const int bid = blockIdx.x;
  const int h  = bid & 15;
  const int qt = (bid >> 4) & 31;
  const int b  = bid >> 9;
  const int q0 = qt * 64;

  {
    const int row = tid >> 2, dq = (tid & 3) * 16;
    const float4* s4 =
        reinterpret_cast<const float4*>(Qg + (((b * Qn) + q0 + row) * Hn + h) * Dn + dq);
    float4* dst = reinterpret_cast<float4*>(&q_lds[row * 68 + dq]);
#pragma unroll
    for (int i = 0; i < 4; ++i) dst[i] = s4[i];
  }
  {
    const int r = tid >> 3, d0 = (tid & 7) * 8;
    const float* src = Eg + ((r * Hn + h) * Dn + d0);
#pragma unroll
    for (int i = 0; i < 8; ++i) et_lds[(d0 + i) * 33 + r] = src[i];
  }
  __syncthreads();

  const int qloc = w * 16 + qr;
  short8v qhi[2], qlo[2];
#pragma unroll
  for (int dm = 0; dm < 2; ++dm) {
#pragma unroll
    for (int j = 0; j < 8; ++j) {
      const int dl = (j < 4) ? (4 * g + j) : (16 + 4 * g + (j - 4));
      const float x = q_lds[qloc * 68 + dm * 32 + dl];
      const uint16_t hi = bf16rn(x);
      qhi[dm][j] = (short)hi;
      qlo[dm][j] = (short)bf16rn(x - bf16f(hi));
    }
  }

  {
    const int r = tid & 31, q8 = tid >> 5;
    float acc[8] = {0.f, 0.f, 0.f, 0.f, 0.f, 0.f, 0.f, 0.f};
    const float bias = biasg[r * Hn + h];
    for (int d = 0; d < 64; ++d) {
      const float e = et_lds[d * 33 + r];
#pragma unroll
      for (int i = 0; i < 8; ++i) acc[i] += e * q_lds[(q8 * 8 + i) * 68 + d];
    }
#pragma unroll
    for (int i = 0; i < 8; ++i)
      allrel[(q8 * 8 + i) * 33 + r] = 0.125f * (acc[i] + bias);
  }
  __syncthreads();

  const int sdq = tid & 7, srow = (tid >> 3) & 15, stile = tid >> 7;
  const int sg = sdq & 3, sdm = sdq >> 2;
  int koff = (((b * Kn) + stile * 16 + srow) * Hn + h) * Dn + (sdm * 32 + sg * 4);
  const int kslotH = (stile * 2 + sdm) * 64 + (srow + 16 * sg);
  const int kslotL = (4 + stile * 2 + sdm) * 64 + (srow + 16 * sg);
  const int vd = tid & 63, vkq = tid >> 6;
  int voff = (((b * Kn) + vkq * 4) * Hn + h) * Dn + vd;
  const int vslot = (vd >> 4) * 64 + (vd & 15) + 16 * vkq;

  const int qglob = q0 + qloc;
  const int prow = (b * Qn + qglob) * Kn + 4 * g;

  f32x4 acc[4] = {{0.f,0.f,0.f,0.f},{0.f,0.f,0.f,0.f},{0.f,0.f,0.f,0.f},{0.f,0.f,0.f,0.f}};
  float mrun = -1e30f, lrun = 0.f;

  const short8v* kfs = reinterpret_cast<const short8v*>(kfrag);
  const short8v* vfs = reinterpret_cast<const short8v*>(vfrag);

  for (int c = 0; c < 64; ++c) {
    const int kb = c * 32;
    __syncthreads();
    {
      const float4 x0 = *reinterpret_cast<const float4*>(Kg + koff);
      const float4 x1 = *reinterpret_cast<const float4*>(Kg + koff + 16);
      koff += 32 * Hn * Dn;
      const float xs0[4] = {x0.x, x0.y, x0.z, x0.w};
      const float xs1[4] = {x1.x, x1.y, x1.z, x1.w};
      uint16_t hh[8], ll[8];
#pragma unroll
      for (int i = 0; i < 4; ++i) {
        const uint16_t h0 = bf16rn(xs0[i]);
        const uint16_t h1 = bf16rn(xs1[i]);
        hh[i] = h0; hh[4 + i] = h1;
        ll[i] = bf16rn(xs0[i] - bf16f(h0));
        ll[4 + i] = bf16rn(xs1[i] - bf16f(h1));
      }
      uint4 uh, ul;
      uh.x = hh[0] | ((uint32_t)hh[1] << 16); uh.y = hh[2] | ((uint32_t)hh[3] << 16);
      uh.z = hh[4] | ((uint32_t)hh[5] << 16); uh.w = hh[6] | ((uint32_t)hh[7] << 16);
      ul.x = ll[0] | ((uint32_t)ll[1] << 16); ul.y = ll[2] | ((uint32_t)ll[3] << 16);
      ul.z = ll[4] | ((uint32_t)ll[5] << 16); ul.w = ll[6] | ((uint32_t)ll[7] << 16);
      kfrag[kslotH] = uh;
      kfrag[kslotL] = ul;
    }
    {
      float v0[4], v1[4];
#pragma unroll
      for (int i = 0; i < 4; ++i) {
        v0[i] = Vg[voff + i * (Hn * Dn)];
        v1[i] = Vg[voff + 16 * Hn * Dn + i * (Hn * Dn)];
      }
      voff += 32 * Hn * Dn;
      uint4 uv;
      uv.x = bf16rn(v0[0]) | ((uint32_t)bf16rn(v0[1]) << 16);
      uv.y = bf16rn(v0[2]) | ((uint32_t)bf16rn(v0[3]) << 16);
      uv.z = bf16rn(v1[0]) | ((uint32_t)bf16rn(v1[1]) << 16);
      uv.w = bf16rn(v1[2]) | ((uint32_t)bf16rn(v1[3]) << 16);
      vfrag[vslot] = uv;
    }
    __syncthreads();

    f32x4 s0 = {0.f, 0.f, 0.f, 0.f}, s1 = {0.f, 0.f, 0.f, 0.f};
#pragma unroll
    for (int dm = 0; dm < 2; ++dm) {
      const short8v k0h = kfs[(dm) * 64 + lane];
      const short8v k1h = kfs[(2 + dm) * 64 + lane];
      const short8v k0l = kfs[(4 + dm) * 64 + lane];
      const short8v k1l = kfs[(6 + dm) * 64 + lane];
      s0 = __builtin_amdgcn_mfma_f32_16x16x32_bf16(k0h, qhi[dm], s0, 0, 0, 0);
      s1 = __builtin_amdgcn_mfma_f32_16x16x32_bf16(k1h, qhi[dm], s1, 0, 0, 0);
      s0 = __builtin_amdgcn_mfma_f32_16x16x32_bf16(k0h, qlo[dm], s0, 0, 0, 0);
      s1 = __builtin_amdgcn_mfma_f32_16x16x32_bf16(k1h, qlo[dm], s1, 0, 0, 0);
      s0 = __builtin_amdgcn_mfma_f32_16x16x32_bf16(k0l, qhi[dm], s0, 0, 0, 0);
      s1 = __builtin_amdgcn_mfma_f32_16x16x32_bf16(k1l, qhi[dm], s1, 0, 0, 0);
    }

    float sv[8];
    {
      const int ib = prow + kb;
      const int4 i0 = *reinterpret_cast<const int4*>(idsg + ib);
      const int4 i1 = *reinterpret_cast<const int4*>(idsg + ib + 16);
      const int4 m0 = *reinterpret_cast<const int4*>(maskg + ib);
      const int4 m1 = *reinterpret_cast<const int4*>(maskg + ib + 16);
      const int ia0[4] = {i0.x, i0.y, i0.z, i0.w};
      const int ia1[4] = {i1.x, i1.y, i1.z, i1.w};
      const int ma0[4] = {m0.x, m0.y, m0.z, m0.w};
      const int ma1[4] = {m1.x, m1.y, m1.z, m1.w};
#pragma unroll
      for (int r = 0; r < 4; ++r) {
        sv[r]     = 0.125f * s0[r] + allrel[qloc * 33 + ia0[r]] + (ma0[r] ? 0.f : -10000.f);
        sv[4 + r] = 0.125f * s1[r] + allrel[qloc * 33 + ia1[r]] + (ma1[r] ? 0.f : -10000.f);
      }
    }

    float m8 = sv[0];
#pragma unroll
    for (int i = 1; i < 8; ++i) m8 = fmaxf(m8, sv[i]);
    m8 = fmaxf(m8, __shfl_xor(m8, 16));
    m8 = fmaxf(m8, __shfl_xor(m8, 32));
    const float mnew = fmaxf(mrun, m8);
    const float sc = __expf(mrun - mnew);
    mrun = mnew;
    float pv[8];
    float ps = 0.f;
#pragma unroll
    for (int i = 0; i < 8; ++i) { pv[i] = __expf(sv[i] - mnew); ps += pv[i]; }
    ps += __shfl_xor(ps, 16);
    ps += __shfl_xor(ps, 32);
    lrun = lrun * sc + ps;

    f32x4 scv;
#pragma unroll
    for (int r = 0; r < 4; ++r) scv[r] = __shfl(sc, 4 * g + r);
#pragma unroll
    for (int dt = 0; dt < 4; ++dt) acc[dt] *= scv;

    short8v pa;
#pragma unroll
    for (int i = 0; i < 8; ++i) pa[i] = (short)bf16rn(pv[i]);
#pragma unroll
    for (int dt = 0; dt < 4; ++dt)
      acc[dt] = __builtin_amdgcn_mfma_f32_16x16x32_bf16(pa, vfs[dt * 64 + lane], acc[dt], 0, 0, 0);
  }

  const float linv = 1.0f / lrun;
  f32x4 lv;
#pragma unroll
  for (int r = 0; r < 4; ++r) lv[r] = __shfl(linv, 4 * g + r);
#pragma unroll
  for (int dt = 0; dt < 4; ++dt) {
#pragma unroll
    for (int r = 0; r < 4; ++r) {
      const int qrow = q0 + w * 16 + 4 * g + r;
      outg[(((b * Qn) + qrow) * Hn + h) * Dn + dt * 16 + qr] = acc[dt][r] * lv[r];
    }
  }
}

extern "C" void kernel_launch(void* const* d_in, const int* in_sizes, int n_in,
                              void* d_out, int out_size, void* d_ws, size_t ws_size,
                              hipStream_t stream) {
  const float* Qg    = (const float*)d_in[0];
  const float* Kg    = (const float*)d_in[1];
  const float* Vg    = (const float*)d_in[2];
  const int*   maskg = (const int*)d_in[3];
  const int*   idsg  = (const int*)d_in[4];
  const float* Eg    = (const float*)d_in[5];
  const float* biasg = (const float*)d_in[6];
  float* outg = (float*)d_out;

  // ws layout
  const size_t oPack = 0;                 // 8,388,608
  const size_t oK    = 8388608;           // +16,777,216 -> 25,165,824
  const size_t need6 = 25165824;
  const int n4 = (Bn * Qn * Kn) / 4;

  uint8_t* ws = (uint8_t*)d_ws;

  if (ws_size >= need6) {
    pack_kernel<<<n4 / 256, 256, 0, stream>>>(idsg, maskg, (uint32_t*)(ws + oPack), n4);
    kfrag6_kernel<<<Bn * Hn * 64, 256, 0, stream>>>(Kg, Vg, ws + oK);
    attn7_kernel<<<Bn * Hn * (Qn / 128), 256, 0, stream>>>(
        Qg, Eg, biasg, ws + oPack, ws + oK, outg);
  } else {
    attn_old_kernel<<<Bn * Hn * (Qn / 64), 256, 0, stream>>>(
        Qg, Kg, Vg, maskg, idsg, Eg, biasg, outg);
  }
}